// Round 7
// baseline (485.535 us; speedup 1.0000x reference)
//
#include <hip/hip_runtime.h>
#include <hip/hip_fp16.h>
#include <math.h>

#define HW_ (512*512)
#define CSTRIDE 32   // doubles between accumulator slots (256 B)

typedef float vf4 __attribute__((ext_vector_type(4)));

// ---------- wave (64-lane) butterfly sum ----------
__device__ __forceinline__ float wred(float v){
#pragma unroll
  for (int o = 32; o > 0; o >>= 1) v += __shfl_xor(v, o, 64);
  return v;
}

// ---------- tap loader: 2 channels (c0, c0+1) at pixel (y,x) ----------
template<bool TR>
__device__ __forceinline__ float2 tap(const void* __restrict__ f, int y, int x, int c0){
  if (TR){
    const __half2* p = (const __half2*)f + (((size_t)((y << 9) + x)) << 6) + (c0 >> 1);
    return __half22float2(*p);
  } else {
    const float* ff = (const float*)f;
    int base = (y << 9) + x;
    float2 r;
    r.x = ff[(size_t)c0 * HW_ + base];
    r.y = ff[(size_t)(c0 + 1) * HW_ + base];
    return r;
  }
}

// ---------- f + sobel-gradient bilinear samples from a 4x4 patch ----------
__device__ __forceinline__ void fgrad(const float P[16], float w00, float w01, float w10, float w11,
                                      float& f, float& gx, float& gy){
  f = w00*P[5] + w01*P[6] + w10*P[9] + w11*P[10];
  float gx11 = (P[2]  + 2.f*P[6]  + P[10] - P[0] - 2.f*P[4]  - P[8] ) * 0.125f;
  float gx12 = (P[3]  + 2.f*P[7]  + P[11] - P[1] - 2.f*P[5]  - P[9] ) * 0.125f;
  float gx21 = (P[6]  + 2.f*P[10] + P[14] - P[4] - 2.f*P[8]  - P[12]) * 0.125f;
  float gx22 = (P[7]  + 2.f*P[11] + P[15] - P[5] - 2.f*P[9]  - P[13]) * 0.125f;
  gx = w00*gx11 + w01*gx12 + w10*gx21 + w11*gx22;
  float gy11 = (P[8]  + 2.f*P[9]  + P[10] - P[0] - 2.f*P[1]  - P[2] ) * 0.125f;
  float gy12 = (P[9]  + 2.f*P[10] + P[11] - P[1] - 2.f*P[2]  - P[3] ) * 0.125f;
  float gy21 = (P[12] + 2.f*P[13] + P[14] - P[4] - 2.f*P[5]  - P[6] ) * 0.125f;
  float gy22 = (P[13] + 2.f*P[14] + P[15] - P[5] - 2.f*P[6]  - P[7] ) * 0.125f;
  gy = w00*gy11 + w01*gy12 + w10*gy21 + w11*gy22;
}

// ---------- cost at a point with RAW fref (normalizes via same wred batch) ----------
template<bool TR>
__device__ __forceinline__ float cost_point_raw(const void* __restrict__ fmap,
                                                const float* __restrict__ fref,
                                                int n, float px, float py, int lane){
  int c0 = 2 * lane;
  float x0f = fminf(fmaxf(floorf(px), 0.f), 511.f);
  float y0f = fminf(fmaxf(floorf(py), 0.f), 511.f);
  int x0 = (int)x0f, y0 = (int)y0f;
  int x1 = min(x0 + 1, 511), y1 = min(y0 + 1, 511);
  float wx = px - x0f, wy = py - y0f;
  float w00 = (1.f-wx)*(1.f-wy), w01 = wx*(1.f-wy), w10 = (1.f-wx)*wy, w11 = wx*wy;
  float2 a = tap<TR>(fmap, y0, x0, c0), b = tap<TR>(fmap, y0, x1, c0);
  float2 c = tap<TR>(fmap, y1, x0, c0), d = tap<TR>(fmap, y1, x1, c0);
  float f0 = w00*a.x + w01*b.x + w10*c.x + w11*d.x;
  float f1 = w00*a.y + w01*b.y + w10*c.y + w11*d.y;
  const float2 fr = *(const float2*)(fref + (size_t)n*128 + c0);
  float Sff  = wred(f0*f0 + f1*f1);
  float Sffr = wred(f0*fr.x + f1*fr.y);
  float Sfr  = wred(fr.x*fr.x + fr.y*fr.y);
  float inv = 1.f / fmaxf(sqrtf(Sff), 1e-12f);
  float irn = 1.f / fmaxf(sqrtf(Sfr), 1e-12f);
  return Sff*inv*inv - 2.f*Sffr*inv*irn + Sfr*irn*irn;
}

// ---------- transpose (C,H,W) fp32 -> (H*W, C) fp16 ----------
// Block: 128 ch x 256 px; 64 KB fp16 LDS tile [px][ch ^ (px & 0x78)].
// Reads: 1 KB chunks per channel row. Writes: full 256 B pixel rows (no sector waste).
__global__ __launch_bounds__(512) void transpose_kernel(const float* __restrict__ fq,
                                                        __half* __restrict__ ftr,
                                                        double* __restrict__ cur2){
  __shared__ __half tile[256 * 128];
  int t = threadIdx.x;
  if (blockIdx.x == 0 && t < 32) cur2[t * CSTRIDE] = 0.0;
  int sb = blockIdx.x << 8;           // 256-px stripe base
  int l = t & 63, r = t >> 6;         // lane, wave(row-group)
  int px0 = l << 2;
#pragma unroll
  for (int p = 0; p < 16; p++){
    int ch = p * 8 + r;
    vf4 v = __builtin_nontemporal_load((const vf4*)(fq + (size_t)ch * HW_ + sb + px0));
#pragma unroll
    for (int j = 0; j < 4; j++){
      int px = px0 + j;
      tile[px * 128 + (ch ^ (px & 0x78))] = __float2half(v[j]);
    }
  }
  __syncthreads();
#pragma unroll
  for (int p = 0; p < 8; p++){
    int px = p * 32 + (t >> 4);
    int c8 = (t & 15) << 3;
    int cs = c8 ^ (px & 0x78);
    uint4 v = *(const uint4*)&tile[px * 128 + cs];
    *(uint4*)(ftr + ((size_t)(sb + px) << 7) + c8) = v;
  }
}

// ---------- fallback accumulator init (when no workspace for ftr) ----------
__global__ void init_kernel(double* __restrict__ cur2){
  if (threadIdx.x < 32) cur2[threadIdx.x * CSTRIDE] = 0.0;
}

// ---------- per-point gather: 16 taps -> 10 lane-partial sums ----------
template<bool TR>
__device__ __forceinline__ bool gather_pt(
    const float* __restrict__ p3D, const float* __restrict__ fref,
    const void* __restrict__ fmap, const float* Rl, const float* Tl,
    float fx, float fy, float cx, float cy,
    int n, int lane, float s[10], float& X, float& Y, float& D)
{
  float PX = p3D[3*n], PY = p3D[3*n+1], PZ = p3D[3*n+2];
  X = Rl[0]*PX + Rl[1]*PY + Rl[2]*PZ + Tl[0];
  Y = Rl[3]*PX + Rl[4]*PY + Rl[5]*PZ + Tl[1];
  D = Rl[6]*PX + Rl[7]*PY + Rl[8]*PZ + Tl[2];
  float px = X / D * fx + cx;
  float py = Y / D * fy + cy;
  if (!(px >= 1.f && px < 511.f && py >= 1.f && py < 511.f)) return false;
  int c0 = 2 * lane;
  float x0f = fminf(fmaxf(floorf(px), 0.f), 511.f);
  float y0f = fminf(fmaxf(floorf(py), 0.f), 511.f);
  int x0 = (int)x0f, y0 = (int)y0f;
  int x1 = min(x0 + 1, 511), y1 = min(y0 + 1, 511);
  float wx = px - x0f, wy = py - y0f;
  int xs[4] = {max(x0-1,0), x0, x1, min(x1+1,511)};
  int ys[4] = {max(y0-1,0), y0, y1, min(y1+1,511)};
  float Pa[16], Pb[16];
#pragma unroll
  for (int rr = 0; rr < 4; rr++)
#pragma unroll
    for (int sc = 0; sc < 4; sc++){
      float2 v = tap<TR>(fmap, ys[rr], xs[sc], c0);
      Pa[rr*4+sc] = v.x; Pb[rr*4+sc] = v.y;
    }
  float w00 = (1.f-wx)*(1.f-wy), w01 = wx*(1.f-wy), w10 = (1.f-wx)*wy, w11 = wx*wy;
  float f0, gx0, gy0, f1, gx1, gy1;
  fgrad(Pa, w00, w01, w10, w11, f0, gx0, gy0);
  fgrad(Pb, w00, w01, w10, w11, f1, gx1, gy1);
  const float2 fr = *(const float2*)(fref + (size_t)n*128 + c0);
  s[0] = f0*f0 + f1*f1;
  s[1] = f0*fr.x + f1*fr.y;
  s[2] = fr.x*fr.x + fr.y*fr.y;
  s[3] = f0*gx0 + f1*gx1;
  s[4] = f0*gy0 + f1*gy1;
  s[5] = gx0*fr.x + gx1*fr.y;
  s[6] = gy0*fr.x + gy1*fr.y;
  s[7] = gx0*gx0 + gx1*gx1;
  s[8] = gx0*gy0 + gx1*gy1;
  s[9] = gy0*gy0 + gy1*gy1;
  return true;
}

// ---------- per-lane slot value from reduced sums ----------
__device__ __forceinline__ float slot_val(const float s[10], float X, float Y, float D,
                                          float fx, float fy, int lane, int li, int lj,
                                          float& se2)
{
  float inv = 1.f / fmaxf(sqrtf(s[0]), 1e-12f);
  float irn = 1.f / fmaxf(sqrtf(s[2]), 1e-12f);
  float inv2 = inv*inv, inv3 = inv2*inv, inv4 = inv2*inv2;
  float Sffr = s[1]*irn, Sgxfr = s[5]*irn, Sgyfr = s[6]*irn, Sfr = s[2]*irn*irn;
  se2 = s[0]*inv2 - 2.f*Sffr*inv + Sfr;
  float gex = s[3]*inv2 - Sgxfr*inv - s[3]*s[0]*inv4 + s[3]*Sffr*inv3;
  float gey = s[4]*inv2 - Sgyfr*inv - s[4]*s[0]*inv4 + s[4]*Sffr*inv3;
  float sxx = s[7]*inv2 - s[3]*s[3]*inv4;
  float sxy = s[8]*inv2 - s[3]*s[4]*inv4;
  float syy = s[9]*inv2 - s[4]*s[4]*inv4;
  float invD = 1.f / D;
  float rx = X * invD, ry = Y * invD;
  float A[6] = {fx*invD, 0.f, -fx*rx*invD, -fx*rx*ry, fx*(1.f+rx*rx), -fx*ry};
  float B[6] = {0.f, fy*invD, -fy*ry*invD, -fy*(1.f+ry*ry), fy*rx*ry, fy*rx};
  float val = 0.f;
  if (lane < 6)        val = A[lane]*gex + B[lane]*gey;
  else if (lane < 27)  val = A[li]*A[lj]*sxx + (A[li]*B[lj] + A[lj]*B[li])*sxy + B[li]*B[lj]*syy;
  else if (lane == 27) val = se2;
  else if (lane == 28) val = 1.f;
  return val;
}

// ---------- fused eval: 2 points/wave, batched wreds, atomic accumulation ----------
template<bool TR>
__global__ __launch_bounds__(512) void eval_kernel(
    const float* __restrict__ p3D, const float* __restrict__ fref,
    const void* __restrict__ fmap, const float* __restrict__ Km,
    const float* __restrict__ Rm, const float* __restrict__ tm,
    double* __restrict__ cur2, float* __restrict__ cost_out, int N)
{
  int t = threadIdx.x;
  int lane = t & 63;
  int wv = t >> 6;
  int gw = blockIdx.x * 8 + wv;
  int n0 = gw * 2, n1 = n0 + 1;
  float fx = Km[0], fy = Km[4], cx = Km[2], cy = Km[5];
  float Rl[9], Tl[3];
#pragma unroll
  for (int i = 0; i < 9; i++) Rl[i] = Rm[i];
#pragma unroll
  for (int i = 0; i < 3; i++) Tl[i] = tm[i];
  int li = 0, lj = 0;
  {
    const int pi_[21] = {0,0,0,0,0,0,1,1,1,1,1,2,2,2,2,3,3,3,4,4,5};
    const int pj_[21] = {0,1,2,3,4,5,1,2,3,4,5,2,3,4,5,3,4,5,4,5,5};
    if (lane >= 6 && lane < 27){ li = pi_[lane-6]; lj = pj_[lane-6]; }
  }
  float sA[10], sB[10];
  float XA=0, YA=0, DA=1, XB=0, YB=0, DB=1;
  bool vA = false, vB = false;
  if (n0 < N) vA = gather_pt<TR>(p3D, fref, fmap, Rl, Tl, fx, fy, cx, cy, n0, lane, sA, XA, YA, DA);
  if (n1 < N) vB = gather_pt<TR>(p3D, fref, fmap, Rl, Tl, fx, fy, cx, cy, n1, lane, sB, XB, YB, DB);
  if (vA){
#pragma unroll
    for (int i = 0; i < 10; i++) sA[i] = wred(sA[i]);
  }
  if (vB){
#pragma unroll
    for (int i = 0; i < 10; i++) sB[i] = wred(sB[i]);
  }
  double acc = 0.0;
  float se2A = 0.f, se2B = 0.f;
  if (vA) acc += (double)slot_val(sA, XA, YA, DA, fx, fy, lane, li, lj, se2A);
  if (vB) acc += (double)slot_val(sB, XB, YB, DB, fx, fy, lane, li, lj, se2B);
  if (cost_out && lane == 0){
    const float nanv = __int_as_float(0x7fc00000);
    if (n0 < N) cost_out[n0] = vA ? se2A : nanv;
    if (n1 < N) cost_out[n1] = vB ? se2B : nanv;
  }
  __shared__ double red[8][32];
  if (lane < 32) red[wv][lane] = acc;
  __syncthreads();
  if (t < 32){
    double ssum = 0.0;
#pragma unroll
    for (int i = 0; i < 8; i++) ssum += red[i][t];
    if (ssum != 0.0) atomicAdd(&cur2[t * CSTRIDE], ssum);
  }
}

// ---------- light trial-cost eval (iter 7: only cost needed) ----------
template<bool TR>
__global__ __launch_bounds__(512) void cost_kernel(
    const float* __restrict__ p3D, const float* __restrict__ fref,
    const void* __restrict__ fmap, const float* __restrict__ Km,
    const float* __restrict__ Rm, const float* __restrict__ tm,
    double* __restrict__ cur2, int N)
{
  int t = threadIdx.x;
  int lane = t & 63;
  int wv = t >> 6;
  int gw = blockIdx.x * 8 + wv;
  int n0 = gw * 2, n1 = n0 + 1;
  float fx = Km[0], fy = Km[4], cx = Km[2], cy = Km[5];
  float Rl[9], Tl[3];
#pragma unroll
  for (int i = 0; i < 9; i++) Rl[i] = Rm[i];
#pragma unroll
  for (int i = 0; i < 3; i++) Tl[i] = tm[i];
  double accc = 0.0, accn = 0.0;
#pragma unroll
  for (int q = 0; q < 2; q++){
    int n = q ? n1 : n0;
    if (n >= N) continue;
    float PX = p3D[3*n], PY = p3D[3*n+1], PZ = p3D[3*n+2];
    float X = Rl[0]*PX + Rl[1]*PY + Rl[2]*PZ + Tl[0];
    float Y = Rl[3]*PX + Rl[4]*PY + Rl[5]*PZ + Tl[1];
    float D = Rl[6]*PX + Rl[7]*PY + Rl[8]*PZ + Tl[2];
    float px = X / D * fx + cx, py = Y / D * fy + cy;
    if (px >= 1.f && px < 511.f && py >= 1.f && py < 511.f){
      float cp = cost_point_raw<TR>(fmap, fref, n, px, py, lane);
      accc += (double)cp; accn += 1.0;
    }
  }
  double acc = (lane == 27) ? accc : ((lane == 28) ? accn : 0.0);
  __shared__ double red[8][32];
  if (lane < 32) red[wv][lane] = acc;
  __syncthreads();
  if (t < 32){
    double ssum = 0.0;
#pragma unroll
    for (int i = 0; i < 8; i++) ssum += red[i][t];
    if (ssum != 0.0) atomicAdd(&cur2[t * CSTRIDE], ssum);
  }
}

// ---------- LM solve from cached raw sums; writes trial pose to state[12..23] ----------
__device__ void solve_step(const double* __restrict__ cur, float* __restrict__ state){
  const int pi_[21] = {0,0,0,0,0,0,1,1,1,1,1,2,2,2,2,3,3,3,4,4,5};
  const int pj_[21] = {0,1,2,3,4,5,1,2,3,4,5,2,3,4,5,3,4,5,4,5,5};
  double rg[6]; for (int i = 0; i < 6; i++) rg[i] = cur[i];
  double rh[6][6];
  for (int k = 0; k < 21; k++){ rh[pi_[k]][pj_[k]] = cur[6+k]; rh[pj_[k]][pi_[k]] = cur[6+k]; }
  float jac[6];
  for (int j = 0; j < 6; j++) jac[j] = state[24+j];
  double lam = (double)state[30];
  double H[6][7];
  for (int i = 0; i < 6; i++)
    for (int j = 0; j < 6; j++) H[i][j] = (double)jac[i] * (double)jac[j] * rh[i][j];
  for (int i = 0; i < 6; i++) H[i][i] += (H[i][i] + 1e-9) * lam;
  for (int i = 0; i < 6; i++) H[i][6] = -((double)jac[i] * rg[i]);
  for (int k = 0; k < 6; k++){
    int p = k; double mx = fabs(H[k][k]);
    for (int r = k+1; r < 6; r++) if (fabs(H[r][k]) > mx){ mx = fabs(H[r][k]); p = r; }
    if (p != k) for (int c = k; c < 7; c++){ double tmp = H[k][c]; H[k][c] = H[p][c]; H[p][c] = tmp; }
    double inv = 1.0 / H[k][k];
    for (int r = k+1; r < 6; r++){
      double m = H[r][k] * inv;
      for (int c = k; c < 7; c++) H[r][c] -= m * H[k][c];
    }
  }
  double d[6];
  for (int i = 5; i >= 0; i--){
    double sx = H[i][6];
    for (int c = i+1; c < 6; c++) sx -= H[i][c] * d[c];
    d[i] = sx / H[i][i];
  }
  for (int j = 0; j < 6; j++) d[j] *= (double)jac[j];
  double wx = d[3], wy = d[4], wz = d[5];
  double th2 = wx*wx + wy*wy + wz*wz, th = sqrt(th2);
  double Aa, Bb;
  if (th < 1e-7){ Aa = 1.0; Bb = 0.5; } else { Aa = sin(th)/th; Bb = (1.0 - cos(th))/th2; }
  double W[3][3] = {{0,-wz,wy},{wz,0,-wx},{-wy,wx,0}};
  double W2[3][3];
  for (int i = 0; i < 3; i++) for (int j = 0; j < 3; j++){
    double q = 0; for (int k = 0; k < 3; k++) q += W[i][k]*W[k][j]; W2[i][j] = q;
  }
  double dr[3][3];
  for (int i = 0; i < 3; i++) for (int j = 0; j < 3; j++)
    dr[i][j] = (i == j ? 1.0 : 0.0) + Aa*W[i][j] + Bb*W2[i][j];
  double Rc[3][3], tc[3];
  for (int i = 0; i < 3; i++){ tc[i] = state[9+i]; for (int j = 0; j < 3; j++) Rc[i][j] = state[i*3+j]; }
  for (int i = 0; i < 3; i++){
    for (int j = 0; j < 3; j++){
      double q = 0; for (int k = 0; k < 3; k++) q += dr[i][k]*Rc[k][j];
      state[12 + i*3 + j] = (float)q;
    }
    double q = 0; for (int k = 0; k < 3; k++) q += dr[i][k]*tc[k];
    state[21 + i] = (float)(q + d[i]);
  }
}

// ---------- consume accumulators; accept/reject; next solve ----------
// iter == -1: init state from Rin/tin, jacobi, cost_best, first solve.
__global__ void update_kernel(double* __restrict__ cur2, float* __restrict__ state,
                              double* __restrict__ cur,
                              const float* __restrict__ Rin, const float* __restrict__ tin,
                              int iter)
{
  if (threadIdx.x != 0) return;
  double tot[32];
  for (int i = 0; i < 32; i++){ tot[i] = cur2[i * CSTRIDE]; cur2[i * CSTRIDE] = 0.0; }
  if (iter < 0){
    for (int i = 0; i < 9; i++) state[i] = Rin[i];
    for (int i = 0; i < 3; i++) state[9+i] = tin[i];
    state[30] = 0.01f;
    const int diag_k[6] = {0, 6, 11, 15, 18, 20};
    for (int j = 0; j < 6; j++)
      state[24+j] = 1.0f / (1.0f + (float)sqrt(tot[6 + diag_k[j]]));
    state[31] = (float)(tot[27] / tot[28]);
    for (int k = 0; k < 32; k++) cur[k] = tot[k];
    solve_step(cur, state);
  } else {
    float cn = (float)(tot[27] / tot[28]);
    bool acpt = (cn <= state[31]);
    float lam = state[30] * (acpt ? 0.1f : 10.f);
    state[30] = fminf(fmaxf(lam, 1e-8f), 1e4f);
    if (acpt){
      for (int i = 0; i < 12; i++) state[i] = state[12+i];
      state[31] = cn;
      for (int k = 0; k < 32; k++) cur[k] = tot[k];
    }
    if (iter < 7) solve_step(cur, state);
  }
}

// ---------- final outputs: R, t, cost_final ----------
template<bool TR>
__global__ __launch_bounds__(256) void final_kernel(
    const float* __restrict__ p3D, const float* __restrict__ fref,
    const void* __restrict__ fmap, const float* __restrict__ Km,
    const float* __restrict__ state, float* __restrict__ out, int N)
{
  if (blockIdx.x == 0 && threadIdx.x < 12) out[threadIdx.x] = state[threadIdx.x];
  int lane = threadIdx.x & 63;
  int n = blockIdx.x * 4 + (threadIdx.x >> 6);
  if (n >= N) return;
  float fx = Km[0], fy = Km[4], cx = Km[2], cy = Km[5];
  float PX = p3D[3*n], PY = p3D[3*n+1], PZ = p3D[3*n+2];
  float X = state[0]*PX + state[1]*PY + state[2]*PZ + state[9];
  float Y = state[3]*PX + state[4]*PY + state[5]*PZ + state[10];
  float D = state[6]*PX + state[7]*PY + state[8]*PZ + state[11];
  float px = X / D * fx + cx, py = Y / D * fy + cy;
  bool vf = (px >= 1.f && px < 511.f && py >= 1.f && py < 511.f);
  float cf = __int_as_float(0x7fc00000);
  if (vf) cf = cost_point_raw<TR>(fmap, fref, n, px, py, lane);
  if (lane == 0) out[12 + N + n] = cf;
}

extern "C" void kernel_launch(void* const* d_in, const int* in_sizes, int n_in,
                              void* d_out, int out_size, void* d_ws, size_t ws_size,
                              hipStream_t stream)
{
  const float* p3D  = (const float*)d_in[0];
  const float* fref = (const float*)d_in[1];
  const float* fq   = (const float*)d_in[2];
  const float* Km   = (const float*)d_in[3];
  const float* Rin  = (const float*)d_in[4];
  const float* tin  = (const float*)d_in[5];
  float* out = (float*)d_out;
  int N = in_sizes[0] / 3;
  int NEB   = (N + 15) / 16;  // eval blocks: 512 thr, 8 waves, 2 pts/wave
  int NBLK4 = (N + 3) / 4;    // final blocks

  char* w = (char*)d_ws;
  float*  state = (float*)w;                    // 256 B
  double* cur   = (double*)(w + 256);           // 256 B (accepted sums cache)
  double* cur2  = (double*)(w + 512);           // 8 KB strided accumulators
  size_t ftr_off = (512 + 32 * CSTRIDE * 8 + 255) & ~(size_t)255;
  __half* ftr = (__half*)(w + ftr_off);
  size_t need = ftr_off + (size_t)HW_ * 128 * 2;
  bool tr = (ws_size >= need);

  if (tr) transpose_kernel<<<HW_/256, 512, 0, stream>>>(fq, ftr, cur2);
  else    init_kernel<<<1, 64, 0, stream>>>(cur2);
  const void* fmap = tr ? (const void*)ftr : (const void*)fq;

  // initial eval at (Rin, tin): emits cost_init, fills accumulators
  if (tr) eval_kernel<true ><<<NEB, 512, 0, stream>>>(p3D, fref, fmap, Km, Rin, tin, cur2, out + 12, N);
  else    eval_kernel<false><<<NEB, 512, 0, stream>>>(p3D, fref, fmap, Km, Rin, tin, cur2, out + 12, N);
  update_kernel<<<1, 64, 0, stream>>>(cur2, state, cur, Rin, tin, -1);

  for (int it = 0; it < 7; it++){
    if (tr) eval_kernel<true ><<<NEB, 512, 0, stream>>>(p3D, fref, fmap, Km, state + 12, state + 21, cur2, nullptr, N);
    else    eval_kernel<false><<<NEB, 512, 0, stream>>>(p3D, fref, fmap, Km, state + 12, state + 21, cur2, nullptr, N);
    update_kernel<<<1, 64, 0, stream>>>(cur2, state, cur, Rin, tin, it);
  }
  // iter 7: only the trial cost matters (its grad/Hess would feed a nonexistent iter 8)
  if (tr) cost_kernel<true ><<<NEB, 512, 0, stream>>>(p3D, fref, fmap, Km, state + 12, state + 21, cur2, N);
  else    cost_kernel<false><<<NEB, 512, 0, stream>>>(p3D, fref, fmap, Km, state + 12, state + 21, cur2, N);
  update_kernel<<<1, 64, 0, stream>>>(cur2, state, cur, Rin, tin, 7);

  if (tr) final_kernel<true ><<<NBLK4, 256, 0, stream>>>(p3D, fref, fmap, Km, state, out, N);
  else    final_kernel<false><<<NBLK4, 256, 0, stream>>>(p3D, fref, fmap, Km, state, out, N);
}